// Round 1
// baseline (1160.602 us; speedup 1.0000x reference)
//
#include <hip/hip_runtime.h>
#include <stdint.h>

typedef __bf16 bf16x8 __attribute__((ext_vector_type(8)));
typedef float  f32x4  __attribute__((ext_vector_type(4)));
typedef unsigned short ushort_t;

#define MFMA16(a,b,c) __builtin_amdgcn_mfma_f32_16x16x32_bf16((a),(b),(c),0,0,0)

// ---------- constants ----------
#define BATCH 256
#define NTOK  256
#define DIM   512
#define NH    8
#define HD    64
#define PD    32
#define LTAB  961
#define MROWS (BATCH*NTOK)   // 65536

// workspace layout (bytes)
#define POS_OFF   0                         // 961*8*4
#define RPB_OFF   32768                     // 8*256*256*4 = 2 MB
#define WQKV_OFF  (RPB_OFF + 2097152)       // 1536*512*2
#define WPROJ_OFF (WQKV_OFF + 1572864)      // 512*512*2
#define QKV_OFF   (WPROJ_OFF + 524288)      // 3*256*8*256*64*2 = 192 MB
#define AOUT_OFF  (QKV_OFF + 201326592)     // 65536*512*2 = 64 MB

__device__ __forceinline__ ushort_t f2bf(float f) {
    unsigned int u = __builtin_bit_cast(unsigned int, f);
    u += 0x7FFFu + ((u >> 16) & 1u);
    return (ushort_t)(u >> 16);
}

// ---------- weight transpose + bf16 convert ----------
__global__ __launch_bounds__(256) void convert_w(
    const float* __restrict__ qkv_w, const float* __restrict__ proj_w,
    ushort_t* __restrict__ wqkvT, ushort_t* __restrict__ wprojT)
{
    int i = blockIdx.x * 256 + threadIdx.x;          // < 1536*512
    int n = i >> 9, k = i & 511;
    wqkvT[i] = f2bf(qkv_w[(size_t)k * 1536 + n]);
    if (i < 512 * 512) {
        int n2 = i >> 9, k2 = i & 511;
        wprojT[i] = f2bf(proj_w[(size_t)k2 * 512 + n2]);
    }
}

// ---------- dynamic position bias MLP (fp32) ----------
__device__ __forceinline__ void ln_relu(float* h, const float* __restrict__ g,
                                        const float* __restrict__ bb) {
    float m = 0.f;
#pragma unroll
    for (int j = 0; j < PD; j++) m += h[j];
    m *= (1.0f / PD);
    float v = 0.f;
#pragma unroll
    for (int j = 0; j < PD; j++) { float d = h[j] - m; v += d * d; }
    v *= (1.0f / PD);
    float inv = rsqrtf(v + 1e-5f);
#pragma unroll
    for (int j = 0; j < PD; j++) {
        float xx = (h[j] - m) * inv * g[j] + bb[j];
        h[j] = xx > 0.f ? xx : 0.f;
    }
}

__global__ __launch_bounds__(256) void pos_mlp(
    const float* __restrict__ biases,
    const float* __restrict__ p1_w, const float* __restrict__ p1_b,
    const float* __restrict__ g1, const float* __restrict__ b1,
    const float* __restrict__ p2_w, const float* __restrict__ p2_b,
    const float* __restrict__ g2, const float* __restrict__ b2,
    const float* __restrict__ p3_w, const float* __restrict__ p3_b,
    const float* __restrict__ g3, const float* __restrict__ b3,
    const float* __restrict__ p4_w, const float* __restrict__ p4_b,
    float* __restrict__ pos)
{
    int r = blockIdx.x * 256 + threadIdx.x;
    if (r >= LTAB) return;
    float c0 = biases[r * 2 + 0], c1 = biases[r * 2 + 1];
    float h[PD], h2[PD];
#pragma unroll
    for (int j = 0; j < PD; j++) h[j] = c0 * p1_w[j] + c1 * p1_w[PD + j] + p1_b[j];
    ln_relu(h, g1, b1);
#pragma unroll
    for (int j = 0; j < PD; j++) {
        float s = p2_b[j];
#pragma unroll
        for (int i = 0; i < PD; i++) s += h[i] * p2_w[i * PD + j];
        h2[j] = s;
    }
    ln_relu(h2, g2, b2);
#pragma unroll
    for (int j = 0; j < PD; j++) {
        float s = p3_b[j];
#pragma unroll
        for (int i = 0; i < PD; i++) s += h2[i] * p3_w[i * PD + j];
        h[j] = s;
    }
    ln_relu(h, g3, b3);
#pragma unroll
    for (int j = 0; j < NH; j++) {
        float s = p4_b[j];
#pragma unroll
        for (int i = 0; i < PD; i++) s += h[i] * p4_w[i * NH + j];
        pos[r * NH + j] = s;
    }
}

// ---------- rpb gather: rpb[h][n][m] = pos[rel_idx[n][m]][h] ----------
__global__ __launch_bounds__(256) void rpb_gather(
    const float* __restrict__ pos, const int* __restrict__ rel_idx,
    float* __restrict__ rpb)
{
    int i = blockIdx.x * 256 + threadIdx.x;   // < 65536
    int idx = rel_idx[i];
#pragma unroll
    for (int hh = 0; hh < NH; hh++) rpb[(size_t)hh * 65536 + i] = pos[idx * NH + hh];
}

// ---------- QKV GEMM: x[65536,512]fp32 @ Wt -> q,k [B,H,N,64], vT [B,H,64,N] bf16 ----------
__global__ __launch_bounds__(256) void qkv_gemm(
    const float* __restrict__ x, const ushort_t* __restrict__ wT,
    const float* __restrict__ qkv_b, ushort_t* __restrict__ qkvb)
{
    __shared__ ushort_t As[128][40];   // pad 8 -> 80B row stride
    __shared__ ushort_t Bs[128][40];
    int t = threadIdx.x;
    int bid = blockIdx.x;
    int mt = bid / 12, nt = bid % 12;           // n fastest: A-tile L2 reuse
    int m0 = mt * 128, n0 = nt * 128;
    int lane = t & 63, w = t >> 6;
    int wm = w >> 1, wn = w & 1;
    int lr = lane & 15, lk = lane >> 4;
    f32x4 acc[4][4];
#pragma unroll
    for (int fr = 0; fr < 4; fr++)
#pragma unroll
        for (int fc = 0; fc < 4; fc++) acc[fr][fc] = (f32x4){0.f, 0.f, 0.f, 0.f};

    for (int kt = 0; kt < 16; ++kt) {
        __syncthreads();
#pragma unroll
        for (int i = 0; i < 4; i++) {           // A: 128x32 fp32 -> bf16
            int idx = t + i * 256;
            int row = idx >> 3, c4 = idx & 7;
            const float4 f = *(const float4*)(x + (size_t)(m0 + row) * 512 + kt * 32 + c4 * 4);
            unsigned int lo = (unsigned)f2bf(f.x) | ((unsigned)f2bf(f.y) << 16);
            unsigned int hi = (unsigned)f2bf(f.z) | ((unsigned)f2bf(f.w) << 16);
            uint2 pk; pk.x = lo; pk.y = hi;
            *reinterpret_cast<uint2*>(&As[row][c4 * 4]) = pk;
        }
#pragma unroll
        for (int i = 0; i < 2; i++) {           // B: 128 rows x 32 k bf16
            int idx = t + i * 256;
            int row = idx >> 2, c8 = idx & 3;
            *reinterpret_cast<uint4*>(&Bs[row][c8 * 8]) =
                *reinterpret_cast<const uint4*>(wT + (size_t)(n0 + row) * 512 + kt * 32 + c8 * 8);
        }
        __syncthreads();
        bf16x8 a[4], b[4];
#pragma unroll
        for (int fr = 0; fr < 4; fr++)
            a[fr] = *reinterpret_cast<const bf16x8*>(&As[wm * 64 + fr * 16 + lr][lk * 8]);
#pragma unroll
        for (int fc = 0; fc < 4; fc++)
            b[fc] = *reinterpret_cast<const bf16x8*>(&Bs[wn * 64 + fc * 16 + lr][lk * 8]);
#pragma unroll
        for (int fr = 0; fr < 4; fr++)
#pragma unroll
            for (int fc = 0; fc < 4; fc++)
                acc[fr][fc] = MFMA16(a[fr], b[fc], acc[fr][fc]);
    }
    // epilogue: n -> (s,h,d); q scaled by 0.125; v stored transposed [d][tok]
#pragma unroll
    for (int fc = 0; fc < 4; fc++) {
        int n = n0 + wn * 64 + fc * 16 + lr;
        float bias = qkv_b[n];
        int s = n >> 9, hh = (n >> 6) & 7, d = n & 63;
        float sc = (s == 0) ? 0.125f : 1.0f;
#pragma unroll
        for (int fr = 0; fr < 4; fr++) {
#pragma unroll
            for (int r = 0; r < 4; r++) {
                int m = m0 + wm * 64 + fr * 16 + lk * 4 + r;
                int bg = m >> 8, tok = m & 255;
                float v = (acc[fr][fc][r] + bias) * sc;
                size_t off;
                if (s < 2)
                    off = ((((size_t)s * 256 + bg) * 8 + hh) * 256 + tok) * 64 + d;
                else
                    off = ((((size_t)512 + bg) * 8 + hh) * 64 + d) * 256 + tok;
                qkvb[off] = f2bf(v);
            }
        }
    }
}

// ---------- attention: per (b,h,half-128-rows); waves independent, 32 rows each ----------
__global__ __launch_bounds__(256) void attn_kernel(
    const ushort_t* __restrict__ qkvb, const float* __restrict__ rpb,
    ushort_t* __restrict__ aout)
{
    __shared__ ushort_t Ps[4][32][40];          // wave-private P repack buffer
    int t = threadIdx.x, lane = t & 63, w = t >> 6;
    int bid = blockIdx.x;                       // B*H*2 = 4096
    int qh = bid & 1; int bh = bid >> 1; int hh = bh & 7; int bg = bh >> 3;
    const ushort_t* Qg  = qkvb + (((size_t)bg * 8 + hh) * 256) * 64;
    const ushort_t* Kg  = qkvb + (((size_t)(256 + bg) * 8 + hh) * 256) * 64;
    const ushort_t* VTg = qkvb + (((size_t)(512 + bg) * 8 + hh) * 64) * 256;  // [64][256]
    int lr = lane & 15, lk = lane >> 4;
    int qrow0 = qh * 128 + w * 32;

    bf16x8 qf[2][2];
#pragma unroll
    for (int fr = 0; fr < 2; fr++)
#pragma unroll
        for (int kc = 0; kc < 2; kc++)
            qf[fr][kc] = *reinterpret_cast<const bf16x8*>(
                Qg + (size_t)(qrow0 + fr * 16 + lr) * 64 + kc * 32 + lk * 8);

    f32x4 oacc[2][4];
    float rsum[2][4];
#pragma unroll
    for (int fr = 0; fr < 2; fr++) {
#pragma unroll
        for (int fc = 0; fc < 4; fc++) oacc[fr][fc] = (f32x4){0.f, 0.f, 0.f, 0.f};
#pragma unroll
        for (int r = 0; r < 4; r++) rsum[fr][r] = 0.f;
    }

    for (int kt = 0; kt < 8; ++kt) {
        f32x4 sacc[2][2];
#pragma unroll
        for (int fr = 0; fr < 2; fr++)
#pragma unroll
            for (int fc = 0; fc < 2; fc++) sacc[fr][fc] = (f32x4){0.f, 0.f, 0.f, 0.f};
#pragma unroll
        for (int kc = 0; kc < 2; kc++) {
            bf16x8 kb0 = *reinterpret_cast<const bf16x8*>(
                Kg + (size_t)(kt * 32 + lr) * 64 + kc * 32 + lk * 8);
            bf16x8 kb1 = *reinterpret_cast<const bf16x8*>(
                Kg + (size_t)(kt * 32 + 16 + lr) * 64 + kc * 32 + lk * 8);
            sacc[0][0] = MFMA16(qf[0][kc], kb0, sacc[0][0]);
            sacc[0][1] = MFMA16(qf[0][kc], kb1, sacc[0][1]);
            sacc[1][0] = MFMA16(qf[1][kc], kb0, sacc[1][0]);
            sacc[1][1] = MFMA16(qf[1][kc], kb1, sacc[1][1]);
        }
        // bias + exp + pack P (no max-subtract: logits bounded ~|2|)
#pragma unroll
        for (int fr = 0; fr < 2; fr++)
#pragma unroll
            for (int fc = 0; fc < 2; fc++)
#pragma unroll
                for (int r = 0; r < 4; r++) {
                    int row = qrow0 + fr * 16 + lk * 4 + r;
                    int col = kt * 32 + fc * 16 + lr;
                    float lg = sacc[fr][fc][r] + rpb[((size_t)hh * 256 + row) * 256 + col];
                    float p = __expf(lg);
                    rsum[fr][r] += p;
                    Ps[w][fr * 16 + lk * 4 + r][fc * 16 + lr] = f2bf(p);
                }
        // PV
        bf16x8 pa[2], vb[4];
#pragma unroll
        for (int fr = 0; fr < 2; fr++)
            pa[fr] = *reinterpret_cast<const bf16x8*>(&Ps[w][fr * 16 + lr][lk * 8]);
#pragma unroll
        for (int fc = 0; fc < 4; fc++)
            vb[fc] = *reinterpret_cast<const bf16x8*>(
                VTg + (size_t)(fc * 16 + lr) * 256 + kt * 32 + lk * 8);
#pragma unroll
        for (int fr = 0; fr < 2; fr++)
#pragma unroll
            for (int fc = 0; fc < 4; fc++)
                oacc[fr][fc] = MFMA16(pa[fr], vb[fc], oacc[fr][fc]);
    }
    // reduce rowsum over lanes 0..15 (lr bits)
#pragma unroll
    for (int fr = 0; fr < 2; fr++)
#pragma unroll
        for (int r = 0; r < 4; r++) {
            float s = rsum[fr][r];
            s += __shfl_xor(s, 1); s += __shfl_xor(s, 2);
            s += __shfl_xor(s, 4); s += __shfl_xor(s, 8);
            rsum[fr][r] = s;
        }
#pragma unroll
    for (int fr = 0; fr < 2; fr++)
#pragma unroll
        for (int fc = 0; fc < 4; fc++)
#pragma unroll
            for (int r = 0; r < 4; r++) {
                int tok = qrow0 + fr * 16 + lk * 4 + r;
                int d = fc * 16 + lr;
                float ov = oacc[fr][fc][r] / rsum[fr][r];
                aout[((size_t)bg * 256 + tok) * 512 + hh * 64 + d] = f2bf(ov);
            }
}

// ---------- proj GEMM: aout[65536,512]bf16 @ Wt -> out fp32 ----------
__global__ __launch_bounds__(256) void proj_gemm(
    const ushort_t* __restrict__ ain, const ushort_t* __restrict__ wT,
    const float* __restrict__ proj_b, float* __restrict__ out)
{
    __shared__ ushort_t As[128][40];
    __shared__ ushort_t Bs[128][40];
    int t = threadIdx.x;
    int bid = blockIdx.x;
    int mt = bid / 4, nt = bid % 4;
    int m0 = mt * 128, n0 = nt * 128;
    int lane = t & 63, w = t >> 6;
    int wm = w >> 1, wn = w & 1;
    int lr = lane & 15, lk = lane >> 4;
    f32x4 acc[4][4];
#pragma unroll
    for (int fr = 0; fr < 4; fr++)
#pragma unroll
        for (int fc = 0; fc < 4; fc++) acc[fr][fc] = (f32x4){0.f, 0.f, 0.f, 0.f};

    for (int kt = 0; kt < 16; ++kt) {
        __syncthreads();
#pragma unroll
        for (int i = 0; i < 2; i++) {
            int idx = t + i * 256;
            int row = idx >> 2, c8 = idx & 3;
            *reinterpret_cast<uint4*>(&As[row][c8 * 8]) =
                *reinterpret_cast<const uint4*>(ain + (size_t)(m0 + row) * 512 + kt * 32 + c8 * 8);
        }
#pragma unroll
        for (int i = 0; i < 2; i++) {
            int idx = t + i * 256;
            int row = idx >> 2, c8 = idx & 3;
            *reinterpret_cast<uint4*>(&Bs[row][c8 * 8]) =
                *reinterpret_cast<const uint4*>(wT + (size_t)(n0 + row) * 512 + kt * 32 + c8 * 8);
        }
        __syncthreads();
        bf16x8 a[4], b[4];
#pragma unroll
        for (int fr = 0; fr < 4; fr++)
            a[fr] = *reinterpret_cast<const bf16x8*>(&As[wm * 64 + fr * 16 + lr][lk * 8]);
#pragma unroll
        for (int fc = 0; fc < 4; fc++)
            b[fc] = *reinterpret_cast<const bf16x8*>(&Bs[wn * 64 + fc * 16 + lr][lk * 8]);
#pragma unroll
        for (int fr = 0; fr < 4; fr++)
#pragma unroll
            for (int fc = 0; fc < 4; fc++)
                acc[fr][fc] = MFMA16(a[fr], b[fc], acc[fr][fc]);
    }
#pragma unroll
    for (int fc = 0; fc < 4; fc++) {
        int n = n0 + wn * 64 + fc * 16 + lr;
        float bias = proj_b[n];
#pragma unroll
        for (int fr = 0; fr < 4; fr++)
#pragma unroll
            for (int r = 0; r < 4; r++) {
                int m = m0 + wm * 64 + fr * 16 + lk * 4 + r;
                out[(size_t)m * 512 + n] = acc[fr][fc][r] + bias;
            }
    }
}

extern "C" void kernel_launch(void* const* d_in, const int* in_sizes, int n_in,
                              void* d_out, int out_size, void* d_ws, size_t ws_size,
                              hipStream_t stream) {
    const float* x      = (const float*)d_in[0];
    const float* qkv_w  = (const float*)d_in[1];
    const float* qkv_b  = (const float*)d_in[2];
    const float* proj_w = (const float*)d_in[3];
    const float* proj_b = (const float*)d_in[4];
    const float* p1_w = (const float*)d_in[5];
    const float* p1_b = (const float*)d_in[6];
    const float* g1   = (const float*)d_in[7];
    const float* b1   = (const float*)d_in[8];
    const float* p2_w = (const float*)d_in[9];
    const float* p2_b = (const float*)d_in[10];
    const float* g2   = (const float*)d_in[11];
    const float* b2   = (const float*)d_in[12];
    const float* p3_w = (const float*)d_in[13];
    const float* p3_b = (const float*)d_in[14];
    const float* g3   = (const float*)d_in[15];
    const float* b3   = (const float*)d_in[16];
    const float* p4_w = (const float*)d_in[17];
    const float* p4_b = (const float*)d_in[18];
    const float* biases  = (const float*)d_in[19];
    const int*   rel_idx = (const int*)d_in[20];
    float* out = (float*)d_out;

    char* ws = (char*)d_ws;
    float*    pos    = (float*)(ws + POS_OFF);
    float*    rpb    = (float*)(ws + RPB_OFF);
    ushort_t* wqkvT  = (ushort_t*)(ws + WQKV_OFF);
    ushort_t* wprojT = (ushort_t*)(ws + WPROJ_OFF);
    ushort_t* qkvb   = (ushort_t*)(ws + QKV_OFF);
    ushort_t* aoutb  = (ushort_t*)(ws + AOUT_OFF);

    convert_w<<<dim3(3072), dim3(256), 0, stream>>>(qkv_w, proj_w, wqkvT, wprojT);
    pos_mlp<<<dim3(4), dim3(256), 0, stream>>>(biases, p1_w, p1_b, g1, b1,
                                               p2_w, p2_b, g2, b2,
                                               p3_w, p3_b, g3, b3,
                                               p4_w, p4_b, pos);
    rpb_gather<<<dim3(256), dim3(256), 0, stream>>>(pos, rel_idx, rpb);
    qkv_gemm<<<dim3(512 * 12), dim3(256), 0, stream>>>(x, wqkvT, qkv_b, qkvb);
    attn_kernel<<<dim3(4096), dim3(256), 0, stream>>>(qkvb, rpb, aoutb);
    proj_gemm<<<dim3(512 * 4), dim3(256), 0, stream>>>(aoutb, wprojT, proj_b, out);
}

// Round 2
// 539.706 us; speedup vs baseline: 2.1504x; 2.1504x over previous
//
#include <hip/hip_runtime.h>
#include <stdint.h>

typedef __bf16 bf16x8 __attribute__((ext_vector_type(8)));
typedef float  f32x4  __attribute__((ext_vector_type(4)));
typedef unsigned short ushort_t;

#define MFMA16(a,b,c) __builtin_amdgcn_mfma_f32_16x16x32_bf16((a),(b),(c),0,0,0)

// ---------- constants ----------
#define BATCH 256
#define NTOK  256
#define DIM   512
#define NH    8
#define HD    64
#define PD    32
#define LTAB  961
#define MROWS (BATCH*NTOK)   // 65536

// workspace layout (bytes)
#define POS_OFF   0                         // 961*8*4
#define RPB_OFF   32768                     // 8*256*256*4 = 2 MB
#define WQKV_OFF  (RPB_OFF + 2097152)       // 1536*512*2
#define WPROJ_OFF (WQKV_OFF + 1572864)      // 512*512*2
#define QKV_OFF   (WPROJ_OFF + 524288)      // 3*256*8*256*64*2 = 192 MB
#define AOUT_OFF  (QKV_OFF + 201326592)     // 65536*512*2 = 64 MB

__device__ __forceinline__ ushort_t f2bf(float f) {
    unsigned int u = __builtin_bit_cast(unsigned int, f);
    u += 0x7FFFu + ((u >> 16) & 1u);
    return (ushort_t)(u >> 16);
}

// ---------- weight transpose + bf16 convert ----------
__global__ __launch_bounds__(256) void convert_w(
    const float* __restrict__ qkv_w, const float* __restrict__ proj_w,
    ushort_t* __restrict__ wqkvT, ushort_t* __restrict__ wprojT)
{
    int i = blockIdx.x * 256 + threadIdx.x;          // < 1536*512
    int n = i >> 9, k = i & 511;
    wqkvT[i] = f2bf(qkv_w[(size_t)k * 1536 + n]);
    if (i < 512 * 512) {
        int n2 = i >> 9, k2 = i & 511;
        wprojT[i] = f2bf(proj_w[(size_t)k2 * 512 + n2]);
    }
}

// ---------- dynamic position bias MLP: 32 lanes per row, scalar state ----------
__device__ __forceinline__ float ln_relu_t(float h, int j,
                                           const float* __restrict__ g,
                                           const float* __restrict__ bb) {
    float m = h;
    m += __shfl_xor(m, 1); m += __shfl_xor(m, 2); m += __shfl_xor(m, 4);
    m += __shfl_xor(m, 8); m += __shfl_xor(m, 16);
    m *= (1.0f / PD);
    float d = h - m;
    float v = d * d;
    v += __shfl_xor(v, 1); v += __shfl_xor(v, 2); v += __shfl_xor(v, 4);
    v += __shfl_xor(v, 8); v += __shfl_xor(v, 16);
    v *= (1.0f / PD);
    float x = d * rsqrtf(v + 1e-5f) * g[j] + bb[j];
    return x > 0.f ? x : 0.f;
}

__global__ __launch_bounds__(256) void pos_mlp(
    const float* __restrict__ biases,
    const float* __restrict__ p1_w, const float* __restrict__ p1_b,
    const float* __restrict__ g1, const float* __restrict__ b1,
    const float* __restrict__ p2_w, const float* __restrict__ p2_b,
    const float* __restrict__ g2, const float* __restrict__ b2,
    const float* __restrict__ p3_w, const float* __restrict__ p3_b,
    const float* __restrict__ g3, const float* __restrict__ b3,
    const float* __restrict__ p4_w, const float* __restrict__ p4_b,
    float* __restrict__ pos)
{
    __shared__ float hs[8][33];
    int tid = threadIdx.x;
    int rl = tid >> 5, j = tid & 31;
    int r = blockIdx.x * 8 + rl;
    bool ok = r < LTAB;
    float c0 = ok ? biases[r * 2 + 0] : 0.f;
    float c1 = ok ? biases[r * 2 + 1] : 0.f;

    float h = c0 * p1_w[j] + c1 * p1_w[PD + j] + p1_b[j];
    h = ln_relu_t(h, j, g1, b1);

    hs[rl][j] = h;
    __syncthreads();
    float s = p2_b[j];
#pragma unroll
    for (int i = 0; i < PD; i++) s += hs[rl][i] * p2_w[i * PD + j];
    __syncthreads();
    h = ln_relu_t(s, j, g2, b2);

    hs[rl][j] = h;
    __syncthreads();
    s = p3_b[j];
#pragma unroll
    for (int i = 0; i < PD; i++) s += hs[rl][i] * p3_w[i * PD + j];
    __syncthreads();
    h = ln_relu_t(s, j, g3, b3);

    hs[rl][j] = h;
    __syncthreads();
    if (ok && j < NH) {
        float o = p4_b[j];
#pragma unroll
        for (int i = 0; i < PD; i++) o += hs[rl][i] * p4_w[i * NH + j];
        pos[r * NH + j] = o;
    }
}

// ---------- rpb gather: rpb[h][n][m] = pos[rel_idx[n][m]][h] ----------
__global__ __launch_bounds__(256) void rpb_gather(
    const float* __restrict__ pos, const int* __restrict__ rel_idx,
    float* __restrict__ rpb)
{
    int i = blockIdx.x * 256 + threadIdx.x;   // < 65536
    int idx = rel_idx[i];
#pragma unroll
    for (int hh = 0; hh < NH; hh++) rpb[(size_t)hh * 65536 + i] = pos[idx * NH + hh];
}

// ---------- QKV GEMM: x[65536,512]fp32 @ Wt -> q,k [B,H,N,64], vT [B,H,64,N] bf16 ----------
__global__ __launch_bounds__(256) void qkv_gemm(
    const float* __restrict__ x, const ushort_t* __restrict__ wT,
    const float* __restrict__ qkv_b, ushort_t* __restrict__ qkvb)
{
    __shared__ ushort_t As[128][40];   // pad 8 -> 80B row stride
    __shared__ ushort_t Bs[128][40];
    int t = threadIdx.x;
    int bid = blockIdx.x;
    int mt = bid / 12, nt = bid % 12;           // n fastest: A-tile L2 reuse
    int m0 = mt * 128, n0 = nt * 128;
    int lane = t & 63, w = t >> 6;
    int wm = w >> 1, wn = w & 1;
    int lr = lane & 15, lk = lane >> 4;
    f32x4 acc[4][4];
#pragma unroll
    for (int fr = 0; fr < 4; fr++)
#pragma unroll
        for (int fc = 0; fc < 4; fc++) acc[fr][fc] = (f32x4){0.f, 0.f, 0.f, 0.f};

    for (int kt = 0; kt < 16; ++kt) {
        __syncthreads();
#pragma unroll
        for (int i = 0; i < 4; i++) {           // A: 128x32 fp32 -> bf16
            int idx = t + i * 256;
            int row = idx >> 3, c4 = idx & 7;
            const float4 f = *(const float4*)(x + (size_t)(m0 + row) * 512 + kt * 32 + c4 * 4);
            unsigned int lo = (unsigned)f2bf(f.x) | ((unsigned)f2bf(f.y) << 16);
            unsigned int hi = (unsigned)f2bf(f.z) | ((unsigned)f2bf(f.w) << 16);
            uint2 pk; pk.x = lo; pk.y = hi;
            *reinterpret_cast<uint2*>(&As[row][c4 * 4]) = pk;
        }
#pragma unroll
        for (int i = 0; i < 2; i++) {           // B: 128 rows x 32 k bf16
            int idx = t + i * 256;
            int row = idx >> 2, c8 = idx & 3;
            *reinterpret_cast<uint4*>(&Bs[row][c8 * 8]) =
                *reinterpret_cast<const uint4*>(wT + (size_t)(n0 + row) * 512 + kt * 32 + c8 * 8);
        }
        __syncthreads();
        bf16x8 a[4], b[4];
#pragma unroll
        for (int fr = 0; fr < 4; fr++)
            a[fr] = *reinterpret_cast<const bf16x8*>(&As[wm * 64 + fr * 16 + lr][lk * 8]);
#pragma unroll
        for (int fc = 0; fc < 4; fc++)
            b[fc] = *reinterpret_cast<const bf16x8*>(&Bs[wn * 64 + fc * 16 + lr][lk * 8]);
#pragma unroll
        for (int fr = 0; fr < 4; fr++)
#pragma unroll
            for (int fc = 0; fc < 4; fc++)
                acc[fr][fc] = MFMA16(a[fr], b[fc], acc[fr][fc]);
    }
    // epilogue: n -> (s,h,d); q scaled by 0.125; v stored transposed [d][tok]
#pragma unroll
    for (int fc = 0; fc < 4; fc++) {
        int n = n0 + wn * 64 + fc * 16 + lr;
        float bias = qkv_b[n];
        int s = n >> 9, hh = (n >> 6) & 7, d = n & 63;
        float sc = (s == 0) ? 0.125f : 1.0f;
#pragma unroll
        for (int fr = 0; fr < 4; fr++) {
#pragma unroll
            for (int r = 0; r < 4; r++) {
                int m = m0 + wm * 64 + fr * 16 + lk * 4 + r;
                int bg = m >> 8, tok = m & 255;
                float v = (acc[fr][fc][r] + bias) * sc;
                size_t off;
                if (s < 2)
                    off = ((((size_t)s * 256 + bg) * 8 + hh) * 256 + tok) * 64 + d;
                else
                    off = ((((size_t)512 + bg) * 8 + hh) * 64 + d) * 256 + tok;
                qkvb[off] = f2bf(v);
            }
        }
    }
}

// ---------- attention: per (b,h,half-128-rows); waves independent, 32 rows each ----------
__global__ __launch_bounds__(256) void attn_kernel(
    const ushort_t* __restrict__ qkvb, const float* __restrict__ rpb,
    ushort_t* __restrict__ aout)
{
    __shared__ ushort_t Ps[4][32][40];          // wave-private P repack buffer
    int t = threadIdx.x, lane = t & 63, w = t >> 6;
    int bid = blockIdx.x;                       // B*H*2 = 4096
    int qh = bid & 1; int bh = bid >> 1; int hh = bh & 7; int bg = bh >> 3;
    const ushort_t* Qg  = qkvb + (((size_t)bg * 8 + hh) * 256) * 64;
    const ushort_t* Kg  = qkvb + (((size_t)(256 + bg) * 8 + hh) * 256) * 64;
    const ushort_t* VTg = qkvb + (((size_t)(512 + bg) * 8 + hh) * 64) * 256;  // [64][256]
    int lr = lane & 15, lk = lane >> 4;
    int qrow0 = qh * 128 + w * 32;

    bf16x8 qf[2][2];
#pragma unroll
    for (int fr = 0; fr < 2; fr++)
#pragma unroll
        for (int kc = 0; kc < 2; kc++)
            qf[fr][kc] = *reinterpret_cast<const bf16x8*>(
                Qg + (size_t)(qrow0 + fr * 16 + lr) * 64 + kc * 32 + lk * 8);

    f32x4 oacc[2][4];
    float rsum[2][4];
#pragma unroll
    for (int fr = 0; fr < 2; fr++) {
#pragma unroll
        for (int fc = 0; fc < 4; fc++) oacc[fr][fc] = (f32x4){0.f, 0.f, 0.f, 0.f};
#pragma unroll
        for (int r = 0; r < 4; r++) rsum[fr][r] = 0.f;
    }

    for (int kt = 0; kt < 8; ++kt) {
        f32x4 sacc[2][2];
#pragma unroll
        for (int fr = 0; fr < 2; fr++)
#pragma unroll
            for (int fc = 0; fc < 2; fc++) sacc[fr][fc] = (f32x4){0.f, 0.f, 0.f, 0.f};
#pragma unroll
        for (int kc = 0; kc < 2; kc++) {
            bf16x8 kb0 = *reinterpret_cast<const bf16x8*>(
                Kg + (size_t)(kt * 32 + lr) * 64 + kc * 32 + lk * 8);
            bf16x8 kb1 = *reinterpret_cast<const bf16x8*>(
                Kg + (size_t)(kt * 32 + 16 + lr) * 64 + kc * 32 + lk * 8);
            sacc[0][0] = MFMA16(qf[0][kc], kb0, sacc[0][0]);
            sacc[0][1] = MFMA16(qf[0][kc], kb1, sacc[0][1]);
            sacc[1][0] = MFMA16(qf[1][kc], kb0, sacc[1][0]);
            sacc[1][1] = MFMA16(qf[1][kc], kb1, sacc[1][1]);
        }
        // bias + exp + pack P (no max-subtract: logits bounded ~|2|)
#pragma unroll
        for (int fr = 0; fr < 2; fr++)
#pragma unroll
            for (int fc = 0; fc < 2; fc++)
#pragma unroll
                for (int r = 0; r < 4; r++) {
                    int row = qrow0 + fr * 16 + lk * 4 + r;
                    int col = kt * 32 + fc * 16 + lr;
                    float lg = sacc[fr][fc][r] + rpb[((size_t)hh * 256 + row) * 256 + col];
                    float p = __expf(lg);
                    rsum[fr][r] += p;
                    Ps[w][fr * 16 + lk * 4 + r][fc * 16 + lr] = f2bf(p);
                }
        // PV
        bf16x8 pa[2], vb[4];
#pragma unroll
        for (int fr = 0; fr < 2; fr++)
            pa[fr] = *reinterpret_cast<const bf16x8*>(&Ps[w][fr * 16 + lr][lk * 8]);
#pragma unroll
        for (int fc = 0; fc < 4; fc++)
            vb[fc] = *reinterpret_cast<const bf16x8*>(
                VTg + (size_t)(fc * 16 + lr) * 256 + kt * 32 + lk * 8);
#pragma unroll
        for (int fr = 0; fr < 2; fr++)
#pragma unroll
            for (int fc = 0; fc < 4; fc++)
                oacc[fr][fc] = MFMA16(pa[fr], vb[fc], oacc[fr][fc]);
    }
    // reduce rowsum over lanes 0..15 (lr bits)
#pragma unroll
    for (int fr = 0; fr < 2; fr++)
#pragma unroll
        for (int r = 0; r < 4; r++) {
            float s = rsum[fr][r];
            s += __shfl_xor(s, 1); s += __shfl_xor(s, 2);
            s += __shfl_xor(s, 4); s += __shfl_xor(s, 8);
            rsum[fr][r] = s;
        }
#pragma unroll
    for (int fr = 0; fr < 2; fr++)
#pragma unroll
        for (int fc = 0; fc < 4; fc++)
#pragma unroll
            for (int r = 0; r < 4; r++) {
                int tok = qrow0 + fr * 16 + lk * 4 + r;
                int d = fc * 16 + lr;
                float ov = oacc[fr][fc][r] / rsum[fr][r];
                aout[((size_t)bg * 256 + tok) * 512 + hh * 64 + d] = f2bf(ov);
            }
}

// ---------- proj GEMM: aout[65536,512]bf16 @ Wt -> out fp32 ----------
__global__ __launch_bounds__(256) void proj_gemm(
    const ushort_t* __restrict__ ain, const ushort_t* __restrict__ wT,
    const float* __restrict__ proj_b, float* __restrict__ out)
{
    __shared__ ushort_t As[128][40];
    __shared__ ushort_t Bs[128][40];
    int t = threadIdx.x;
    int bid = blockIdx.x;
    int mt = bid / 4, nt = bid % 4;
    int m0 = mt * 128, n0 = nt * 128;
    int lane = t & 63, w = t >> 6;
    int wm = w >> 1, wn = w & 1;
    int lr = lane & 15, lk = lane >> 4;
    f32x4 acc[4][4];
#pragma unroll
    for (int fr = 0; fr < 4; fr++)
#pragma unroll
        for (int fc = 0; fc < 4; fc++) acc[fr][fc] = (f32x4){0.f, 0.f, 0.f, 0.f};

    for (int kt = 0; kt < 16; ++kt) {
        __syncthreads();
#pragma unroll
        for (int i = 0; i < 2; i++) {
            int idx = t + i * 256;
            int row = idx >> 2, c8 = idx & 3;
            *reinterpret_cast<uint4*>(&As[row][c8 * 8]) =
                *reinterpret_cast<const uint4*>(ain + (size_t)(m0 + row) * 512 + kt * 32 + c8 * 8);
        }
#pragma unroll
        for (int i = 0; i < 2; i++) {
            int idx = t + i * 256;
            int row = idx >> 2, c8 = idx & 3;
            *reinterpret_cast<uint4*>(&Bs[row][c8 * 8]) =
                *reinterpret_cast<const uint4*>(wT + (size_t)(n0 + row) * 512 + kt * 32 + c8 * 8);
        }
        __syncthreads();
        bf16x8 a[4], b[4];
#pragma unroll
        for (int fr = 0; fr < 4; fr++)
            a[fr] = *reinterpret_cast<const bf16x8*>(&As[wm * 64 + fr * 16 + lr][lk * 8]);
#pragma unroll
        for (int fc = 0; fc < 4; fc++)
            b[fc] = *reinterpret_cast<const bf16x8*>(&Bs[wn * 64 + fc * 16 + lr][lk * 8]);
#pragma unroll
        for (int fr = 0; fr < 4; fr++)
#pragma unroll
            for (int fc = 0; fc < 4; fc++)
                acc[fr][fc] = MFMA16(a[fr], b[fc], acc[fr][fc]);
    }
#pragma unroll
    for (int fc = 0; fc < 4; fc++) {
        int n = n0 + wn * 64 + fc * 16 + lr;
        float bias = proj_b[n];
#pragma unroll
        for (int fr = 0; fr < 4; fr++)
#pragma unroll
            for (int r = 0; r < 4; r++) {
                int m = m0 + wm * 64 + fr * 16 + lk * 4 + r;
                out[(size_t)m * 512 + n] = acc[fr][fc][r] + bias;
            }
    }
}

extern "C" void kernel_launch(void* const* d_in, const int* in_sizes, int n_in,
                              void* d_out, int out_size, void* d_ws, size_t ws_size,
                              hipStream_t stream) {
    const float* x      = (const float*)d_in[0];
    const float* qkv_w  = (const float*)d_in[1];
    const float* qkv_b  = (const float*)d_in[2];
    const float* proj_w = (const float*)d_in[3];
    const float* proj_b = (const float*)d_in[4];
    const float* p1_w = (const float*)d_in[5];
    const float* p1_b = (const float*)d_in[6];
    const float* g1   = (const float*)d_in[7];
    const float* b1   = (const float*)d_in[8];
    const float* p2_w = (const float*)d_in[9];
    const float* p2_b = (const float*)d_in[10];
    const float* g2   = (const float*)d_in[11];
    const float* b2   = (const float*)d_in[12];
    const float* p3_w = (const float*)d_in[13];
    const float* p3_b = (const float*)d_in[14];
    const float* g3   = (const float*)d_in[15];
    const float* b3   = (const float*)d_in[16];
    const float* p4_w = (const float*)d_in[17];
    const float* p4_b = (const float*)d_in[18];
    const float* biases  = (const float*)d_in[19];
    const int*   rel_idx = (const int*)d_in[20];
    float* out = (float*)d_out;

    char* ws = (char*)d_ws;
    float*    pos    = (float*)(ws + POS_OFF);
    float*    rpb    = (float*)(ws + RPB_OFF);
    ushort_t* wqkvT  = (ushort_t*)(ws + WQKV_OFF);
    ushort_t* wprojT = (ushort_t*)(ws + WPROJ_OFF);
    ushort_t* qkvb   = (ushort_t*)(ws + QKV_OFF);
    ushort_t* aoutb  = (ushort_t*)(ws + AOUT_OFF);

    convert_w<<<dim3(3072), dim3(256), 0, stream>>>(qkv_w, proj_w, wqkvT, wprojT);
    pos_mlp<<<dim3(121), dim3(256), 0, stream>>>(biases, p1_w, p1_b, g1, b1,
                                                 p2_w, p2_b, g2, b2,
                                                 p3_w, p3_b, g3, b3,
                                                 p4_w, p4_b, pos);
    rpb_gather<<<dim3(256), dim3(256), 0, stream>>>(pos, rel_idx, rpb);
    qkv_gemm<<<dim3(512 * 12), dim3(256), 0, stream>>>(x, wqkvT, qkv_b, qkvb);
    attn_kernel<<<dim3(4096), dim3(256), 0, stream>>>(qkvb, rpb, aoutb);
    proj_gemm<<<dim3(512 * 4), dim3(256), 0, stream>>>(aoutb, wprojT, proj_b, out);
}

// Round 3
// 440.601 us; speedup vs baseline: 2.6341x; 1.2249x over previous
//
#include <hip/hip_runtime.h>
#include <stdint.h>

typedef __bf16 bf16x8 __attribute__((ext_vector_type(8)));
typedef float  f32x4  __attribute__((ext_vector_type(4)));
typedef unsigned short ushort_t;

#define MFMA16(a,b,c) __builtin_amdgcn_mfma_f32_16x16x32_bf16((a),(b),(c),0,0,0)

// async global->LDS, 16B per lane; LDS dest must be wave-uniform base (HW adds lane*16)
#define GLOAD16(gsrc, ldst) \
    __builtin_amdgcn_global_load_lds((const __attribute__((address_space(1))) void*)(gsrc), \
                                     (__attribute__((address_space(3))) void*)(ldst), 16, 0, 0)

// ---------- constants ----------
#define BATCH 256
#define NTOK  256
#define DIM   512
#define NH    8
#define HD    64
#define PD    32
#define LTAB  961
#define MROWS (BATCH*NTOK)   // 65536

// workspace layout (bytes)
#define POS_OFF   0                         // 961*8*4
#define RPB_OFF   32768                     // 8*256*256*4 = 2 MB
#define WQKV_OFF  (RPB_OFF + 2097152)       // 1536*512*2
#define WPROJ_OFF (WQKV_OFF + 1572864)      // 512*512*2
#define QKV_OFF   (WPROJ_OFF + 524288)      // 3*256*8*256*64*2 = 192 MB
#define AOUT_OFF  (QKV_OFF + 201326592)     // 65536*512*2 = 64 MB
#define XB_OFF    AOUT_OFF                  // xb overlays aout: disjoint lifetimes
                                            // (xb: convert_x -> qkv_gemm; aout: attn -> proj)

__device__ __forceinline__ ushort_t f2bf(float f) {
    unsigned int u = __builtin_bit_cast(unsigned int, f);
    u += 0x7FFFu + ((u >> 16) & 1u);
    return (ushort_t)(u >> 16);
}

// ---------- x fp32 -> bf16 (one pass; removes per-tile conversion from qkv_gemm) ----------
__global__ __launch_bounds__(256) void convert_x(
    const float* __restrict__ x, ushort_t* __restrict__ xb)
{
    size_t i = ((size_t)blockIdx.x * 256 + threadIdx.x) * 8;   // 33.5M elements / 8
    float4 f0 = *(const float4*)(x + i);
    float4 f1 = *(const float4*)(x + i + 4);
    uint4 o;
    o.x = (unsigned)f2bf(f0.x) | ((unsigned)f2bf(f0.y) << 16);
    o.y = (unsigned)f2bf(f0.z) | ((unsigned)f2bf(f0.w) << 16);
    o.z = (unsigned)f2bf(f1.x) | ((unsigned)f2bf(f1.y) << 16);
    o.w = (unsigned)f2bf(f1.z) | ((unsigned)f2bf(f1.w) << 16);
    *reinterpret_cast<uint4*>(xb + i) = o;
}

// ---------- weight transpose + bf16 convert ----------
__global__ __launch_bounds__(256) void convert_w(
    const float* __restrict__ qkv_w, const float* __restrict__ proj_w,
    ushort_t* __restrict__ wqkvT, ushort_t* __restrict__ wprojT)
{
    int i = blockIdx.x * 256 + threadIdx.x;          // < 1536*512
    int n = i >> 9, k = i & 511;
    wqkvT[i] = f2bf(qkv_w[(size_t)k * 1536 + n]);
    if (i < 512 * 512) {
        int n2 = i >> 9, k2 = i & 511;
        wprojT[i] = f2bf(proj_w[(size_t)k2 * 512 + n2]);
    }
}

// ---------- dynamic position bias MLP: 32 lanes per row, scalar state ----------
__device__ __forceinline__ float ln_relu_t(float h, int j,
                                           const float* __restrict__ g,
                                           const float* __restrict__ bb) {
    float m = h;
    m += __shfl_xor(m, 1); m += __shfl_xor(m, 2); m += __shfl_xor(m, 4);
    m += __shfl_xor(m, 8); m += __shfl_xor(m, 16);
    m *= (1.0f / PD);
    float d = h - m;
    float v = d * d;
    v += __shfl_xor(v, 1); v += __shfl_xor(v, 2); v += __shfl_xor(v, 4);
    v += __shfl_xor(v, 8); v += __shfl_xor(v, 16);
    v *= (1.0f / PD);
    float x = d * rsqrtf(v + 1e-5f) * g[j] + bb[j];
    return x > 0.f ? x : 0.f;
}

__global__ __launch_bounds__(256) void pos_mlp(
    const float* __restrict__ biases,
    const float* __restrict__ p1_w, const float* __restrict__ p1_b,
    const float* __restrict__ g1, const float* __restrict__ b1,
    const float* __restrict__ p2_w, const float* __restrict__ p2_b,
    const float* __restrict__ g2, const float* __restrict__ b2,
    const float* __restrict__ p3_w, const float* __restrict__ p3_b,
    const float* __restrict__ g3, const float* __restrict__ b3,
    const float* __restrict__ p4_w, const float* __restrict__ p4_b,
    float* __restrict__ pos)
{
    __shared__ float hs[8][33];
    int tid = threadIdx.x;
    int rl = tid >> 5, j = tid & 31;
    int r = blockIdx.x * 8 + rl;
    bool ok = r < LTAB;
    float c0 = ok ? biases[r * 2 + 0] : 0.f;
    float c1 = ok ? biases[r * 2 + 1] : 0.f;

    float h = c0 * p1_w[j] + c1 * p1_w[PD + j] + p1_b[j];
    h = ln_relu_t(h, j, g1, b1);

    hs[rl][j] = h;
    __syncthreads();
    float s = p2_b[j];
#pragma unroll
    for (int i = 0; i < PD; i++) s += hs[rl][i] * p2_w[i * PD + j];
    __syncthreads();
    h = ln_relu_t(s, j, g2, b2);

    hs[rl][j] = h;
    __syncthreads();
    s = p3_b[j];
#pragma unroll
    for (int i = 0; i < PD; i++) s += hs[rl][i] * p3_w[i * PD + j];
    __syncthreads();
    h = ln_relu_t(s, j, g3, b3);

    hs[rl][j] = h;
    __syncthreads();
    if (ok && j < NH) {
        float o = p4_b[j];
#pragma unroll
        for (int i = 0; i < PD; i++) o += hs[rl][i] * p4_w[i * NH + j];
        pos[r * NH + j] = o;
    }
}

// ---------- rpb gather: rpb[h][n][m] = pos[rel_idx[n][m]][h] ----------
__global__ __launch_bounds__(256) void rpb_gather(
    const float* __restrict__ pos, const int* __restrict__ rel_idx,
    float* __restrict__ rpb)
{
    int i = blockIdx.x * 256 + threadIdx.x;   // < 65536
    int idx = rel_idx[i];
#pragma unroll
    for (int hh = 0; hh < NH; hh++) rpb[(size_t)hh * 65536 + i] = pos[idx * NH + hh];
}

// ---------- QKV GEMM: xb[65536,512]bf16 @ Wt -> q,k [B,H,N,64], vT [B,H,64,N] bf16 ----------
// m97 structure: 128x128 tile, BK=32, global_load_lds width-16, linear LDS
__global__ __launch_bounds__(256) void qkv_gemm(
    const ushort_t* __restrict__ xb, const ushort_t* __restrict__ wT,
    const float* __restrict__ qkv_b, ushort_t* __restrict__ qkvb)
{
    __shared__ ushort_t As[128 * 32];   // linear (global_load_lds requires it)
    __shared__ ushort_t Bs[128 * 32];
    int t = threadIdx.x;
    int bid = blockIdx.x;
    int mt = bid / 12, nt = bid % 12;           // n fastest: A-tile L2/L3 reuse
    int m0 = mt * 128, n0 = nt * 128;
    int lane = t & 63, w = t >> 6;
    int wm = w >> 1, wn = w & 1;
    int lr = lane & 15, lk = lane >> 4;
    int srow = lane >> 2, scol = (lane & 3) * 8;   // staging: 16 rows x 64B per chunk
    f32x4 acc[4][4];
#pragma unroll
    for (int fr = 0; fr < 4; fr++)
#pragma unroll
        for (int fc = 0; fc < 4; fc++) acc[fr][fc] = (f32x4){0.f, 0.f, 0.f, 0.f};

    for (int kt = 0; kt < 16; ++kt) {
        __syncthreads();
#pragma unroll
        for (int i = 0; i < 2; i++) {           // wave w stages rows [w*32+i*16, +16)
            int row = w * 32 + i * 16;
            GLOAD16(xb + (size_t)(m0 + row + srow) * 512 + kt * 32 + scol,
                    As + (row) * 32);
            GLOAD16(wT + (size_t)(n0 + row + srow) * 512 + kt * 32 + scol,
                    Bs + (row) * 32);
        }
        asm volatile("s_waitcnt vmcnt(0)" ::: "memory");
        __syncthreads();
        bf16x8 a[4], b[4];
#pragma unroll
        for (int fr = 0; fr < 4; fr++)
            a[fr] = *reinterpret_cast<const bf16x8*>(&As[(wm * 64 + fr * 16 + lr) * 32 + lk * 8]);
#pragma unroll
        for (int fc = 0; fc < 4; fc++)
            b[fc] = *reinterpret_cast<const bf16x8*>(&Bs[(wn * 64 + fc * 16 + lr) * 32 + lk * 8]);
#pragma unroll
        for (int fr = 0; fr < 4; fr++)
#pragma unroll
            for (int fc = 0; fc < 4; fc++)
                acc[fr][fc] = MFMA16(a[fr], b[fc], acc[fr][fc]);
    }
    // epilogue: s = q/k/v is uniform per block (128-wide n-tile never straddles 512)
    int s = n0 >> 9;
    if (s < 2) {
        float sc = (s == 0) ? 0.125f : 1.0f;
#pragma unroll
        for (int fc = 0; fc < 4; fc++) {
            int n = n0 + wn * 64 + fc * 16 + lr;
            float bias = qkv_b[n];
            int hh = (n >> 6) & 7, d = n & 63;
#pragma unroll
            for (int fr = 0; fr < 4; fr++)
#pragma unroll
                for (int r = 0; r < 4; r++) {
                    int m = m0 + wm * 64 + fr * 16 + lk * 4 + r;
                    int bg = m >> 8, tok = m & 255;
                    float v = (acc[fr][fc][r] + bias) * sc;
                    qkvb[((((size_t)s * 256 + bg) * 8 + hh) * 256 + tok) * 64 + d] = f2bf(v);
                }
        }
    } else {
        // V transposed [B,H,64,N]: pack 4 contiguous tokens -> one 8B store
#pragma unroll
        for (int fc = 0; fc < 4; fc++) {
            int n = n0 + wn * 64 + fc * 16 + lr;
            float bias = qkv_b[n];
            int hh = (n >> 6) & 7, d = n & 63;
#pragma unroll
            for (int fr = 0; fr < 4; fr++) {
                int m = m0 + wm * 64 + fr * 16 + lk * 4;   // 4-aligned; bg uniform over r
                int bg = m >> 8, tok = m & 255;
                uint2 pk;
                pk.x = (unsigned)f2bf(acc[fr][fc][0] + bias) |
                       ((unsigned)f2bf(acc[fr][fc][1] + bias) << 16);
                pk.y = (unsigned)f2bf(acc[fr][fc][2] + bias) |
                       ((unsigned)f2bf(acc[fr][fc][3] + bias) << 16);
                *reinterpret_cast<uint2*>(
                    qkvb + ((((size_t)512 + bg) * 8 + hh) * 64 + d) * 256 + tok) = pk;
            }
        }
    }
}

// ---------- attention: per (b,h,half-128-rows); waves independent, 32 rows each ----------
__global__ __launch_bounds__(256) void attn_kernel(
    const ushort_t* __restrict__ qkvb, const float* __restrict__ rpb,
    ushort_t* __restrict__ aout)
{
    __shared__ ushort_t Ps[4][32][40];          // wave-private P repack buffer
    int t = threadIdx.x, lane = t & 63, w = t >> 6;
    int bid = blockIdx.x;                       // B*H*2 = 4096
    int qh = bid & 1; int bh = bid >> 1; int hh = bh & 7; int bg = bh >> 3;
    const ushort_t* Qg  = qkvb + (((size_t)bg * 8 + hh) * 256) * 64;
    const ushort_t* Kg  = qkvb + (((size_t)(256 + bg) * 8 + hh) * 256) * 64;
    const ushort_t* VTg = qkvb + (((size_t)(512 + bg) * 8 + hh) * 64) * 256;  // [64][256]
    int lr = lane & 15, lk = lane >> 4;
    int qrow0 = qh * 128 + w * 32;

    bf16x8 qf[2][2];
#pragma unroll
    for (int fr = 0; fr < 2; fr++)
#pragma unroll
        for (int kc = 0; kc < 2; kc++)
            qf[fr][kc] = *reinterpret_cast<const bf16x8*>(
                Qg + (size_t)(qrow0 + fr * 16 + lr) * 64 + kc * 32 + lk * 8);

    f32x4 oacc[2][4];
    float rsum[2][4];
#pragma unroll
    for (int fr = 0; fr < 2; fr++) {
#pragma unroll
        for (int fc = 0; fc < 4; fc++) oacc[fr][fc] = (f32x4){0.f, 0.f, 0.f, 0.f};
#pragma unroll
        for (int r = 0; r < 4; r++) rsum[fr][r] = 0.f;
    }

    for (int kt = 0; kt < 8; ++kt) {
        f32x4 sacc[2][2];
#pragma unroll
        for (int fr = 0; fr < 2; fr++)
#pragma unroll
            for (int fc = 0; fc < 2; fc++) sacc[fr][fc] = (f32x4){0.f, 0.f, 0.f, 0.f};
#pragma unroll
        for (int kc = 0; kc < 2; kc++) {
            bf16x8 kb0 = *reinterpret_cast<const bf16x8*>(
                Kg + (size_t)(kt * 32 + lr) * 64 + kc * 32 + lk * 8);
            bf16x8 kb1 = *reinterpret_cast<const bf16x8*>(
                Kg + (size_t)(kt * 32 + 16 + lr) * 64 + kc * 32 + lk * 8);
            sacc[0][0] = MFMA16(qf[0][kc], kb0, sacc[0][0]);
            sacc[0][1] = MFMA16(qf[0][kc], kb1, sacc[0][1]);
            sacc[1][0] = MFMA16(qf[1][kc], kb0, sacc[1][0]);
            sacc[1][1] = MFMA16(qf[1][kc], kb1, sacc[1][1]);
        }
        // bias + exp + pack P (no max-subtract: logits bounded ~|2|)
#pragma unroll
        for (int fr = 0; fr < 2; fr++)
#pragma unroll
            for (int fc = 0; fc < 2; fc++)
#pragma unroll
                for (int r = 0; r < 4; r++) {
                    int row = qrow0 + fr * 16 + lk * 4 + r;
                    int col = kt * 32 + fc * 16 + lr;
                    float lg = sacc[fr][fc][r] + rpb[((size_t)hh * 256 + row) * 256 + col];
                    float p = __expf(lg);
                    rsum[fr][r] += p;
                    Ps[w][fr * 16 + lk * 4 + r][fc * 16 + lr] = f2bf(p);
                }
        // PV
        bf16x8 pa[2], vb[4];
#pragma unroll
        for (int fr = 0; fr < 2; fr++)
            pa[fr] = *reinterpret_cast<const bf16x8*>(&Ps[w][fr * 16 + lr][lk * 8]);
#pragma unroll
        for (int fc = 0; fc < 4; fc++)
            vb[fc] = *reinterpret_cast<const bf16x8*>(
                VTg + (size_t)(fc * 16 + lr) * 256 + kt * 32 + lk * 8);
#pragma unroll
        for (int fr = 0; fr < 2; fr++)
#pragma unroll
            for (int fc = 0; fc < 4; fc++)
                oacc[fr][fc] = MFMA16(pa[fr], vb[fc], oacc[fr][fc]);
    }
    // reduce rowsum over lanes 0..15 (lr bits)
#pragma unroll
    for (int fr = 0; fr < 2; fr++)
#pragma unroll
        for (int r = 0; r < 4; r++) {
            float s = rsum[fr][r];
            s += __shfl_xor(s, 1); s += __shfl_xor(s, 2);
            s += __shfl_xor(s, 4); s += __shfl_xor(s, 8);
            rsum[fr][r] = s;
        }
#pragma unroll
    for (int fr = 0; fr < 2; fr++)
#pragma unroll
        for (int fc = 0; fc < 4; fc++)
#pragma unroll
            for (int r = 0; r < 4; r++) {
                int tok = qrow0 + fr * 16 + lk * 4 + r;
                int d = fc * 16 + lr;
                float ov = oacc[fr][fc][r] / rsum[fr][r];
                aout[((size_t)bg * 256 + tok) * 512 + hh * 64 + d] = f2bf(ov);
            }
}

// ---------- proj GEMM: aout[65536,512]bf16 @ Wt -> out fp32 ----------
__global__ __launch_bounds__(256) void proj_gemm(
    const ushort_t* __restrict__ ain, const ushort_t* __restrict__ wT,
    const float* __restrict__ proj_b, float* __restrict__ out)
{
    __shared__ ushort_t As[128 * 32];
    __shared__ ushort_t Bs[128 * 32];
    int t = threadIdx.x;
    int bid = blockIdx.x;
    int mt = bid / 4, nt = bid % 4;
    int m0 = mt * 128, n0 = nt * 128;
    int lane = t & 63, w = t >> 6;
    int wm = w >> 1, wn = w & 1;
    int lr = lane & 15, lk = lane >> 4;
    int srow = lane >> 2, scol = (lane & 3) * 8;
    f32x4 acc[4][4];
#pragma unroll
    for (int fr = 0; fr < 4; fr++)
#pragma unroll
        for (int fc = 0; fc < 4; fc++) acc[fr][fc] = (f32x4){0.f, 0.f, 0.f, 0.f};

    for (int kt = 0; kt < 16; ++kt) {
        __syncthreads();
#pragma unroll
        for (int i = 0; i < 2; i++) {
            int row = w * 32 + i * 16;
            GLOAD16(ain + (size_t)(m0 + row + srow) * 512 + kt * 32 + scol,
                    As + (row) * 32);
            GLOAD16(wT + (size_t)(n0 + row + srow) * 512 + kt * 32 + scol,
                    Bs + (row) * 32);
        }
        asm volatile("s_waitcnt vmcnt(0)" ::: "memory");
        __syncthreads();
        bf16x8 a[4], b[4];
#pragma unroll
        for (int fr = 0; fr < 4; fr++)
            a[fr] = *reinterpret_cast<const bf16x8*>(&As[(wm * 64 + fr * 16 + lr) * 32 + lk * 8]);
#pragma unroll
        for (int fc = 0; fc < 4; fc++)
            b[fc] = *reinterpret_cast<const bf16x8*>(&Bs[(wn * 64 + fc * 16 + lr) * 32 + lk * 8]);
#pragma unroll
        for (int fr = 0; fr < 4; fr++)
#pragma unroll
            for (int fc = 0; fc < 4; fc++)
                acc[fr][fc] = MFMA16(a[fr], b[fc], acc[fr][fc]);
    }
#pragma unroll
    for (int fc = 0; fc < 4; fc++) {
        int n = n0 + wn * 64 + fc * 16 + lr;
        float bias = proj_b[n];
#pragma unroll
        for (int fr = 0; fr < 4; fr++)
#pragma unroll
            for (int r = 0; r < 4; r++) {
                int m = m0 + wm * 64 + fr * 16 + lk * 4 + r;
                out[(size_t)m * 512 + n] = acc[fr][fc][r] + bias;
            }
    }
}

extern "C" void kernel_launch(void* const* d_in, const int* in_sizes, int n_in,
                              void* d_out, int out_size, void* d_ws, size_t ws_size,
                              hipStream_t stream) {
    const float* x      = (const float*)d_in[0];
    const float* qkv_w  = (const float*)d_in[1];
    const float* qkv_b  = (const float*)d_in[2];
    const float* proj_w = (const float*)d_in[3];
    const float* proj_b = (const float*)d_in[4];
    const float* p1_w = (const float*)d_in[5];
    const float* p1_b = (const float*)d_in[6];
    const float* g1   = (const float*)d_in[7];
    const float* b1   = (const float*)d_in[8];
    const float* p2_w = (const float*)d_in[9];
    const float* p2_b = (const float*)d_in[10];
    const float* g2   = (const float*)d_in[11];
    const float* b2   = (const float*)d_in[12];
    const float* p3_w = (const float*)d_in[13];
    const float* p3_b = (const float*)d_in[14];
    const float* g3   = (const float*)d_in[15];
    const float* b3   = (const float*)d_in[16];
    const float* p4_w = (const float*)d_in[17];
    const float* p4_b = (const float*)d_in[18];
    const float* biases  = (const float*)d_in[19];
    const int*   rel_idx = (const int*)d_in[20];
    float* out = (float*)d_out;

    char* ws = (char*)d_ws;
    float*    pos    = (float*)(ws + POS_OFF);
    float*    rpb    = (float*)(ws + RPB_OFF);
    ushort_t* wqkvT  = (ushort_t*)(ws + WQKV_OFF);
    ushort_t* wprojT = (ushort_t*)(ws + WPROJ_OFF);
    ushort_t* qkvb   = (ushort_t*)(ws + QKV_OFF);
    ushort_t* aoutb  = (ushort_t*)(ws + AOUT_OFF);
    ushort_t* xb     = (ushort_t*)(ws + XB_OFF);     // overlays aoutb (disjoint lifetime)

    convert_x<<<dim3(16384), dim3(256), 0, stream>>>(x, xb);
    convert_w<<<dim3(3072), dim3(256), 0, stream>>>(qkv_w, proj_w, wqkvT, wprojT);
    pos_mlp<<<dim3(121), dim3(256), 0, stream>>>(biases, p1_w, p1_b, g1, b1,
                                                 p2_w, p2_b, g2, b2,
                                                 p3_w, p3_b, g3, b3,
                                                 p4_w, p4_b, pos);
    rpb_gather<<<dim3(256), dim3(256), 0, stream>>>(pos, rel_idx, rpb);
    qkv_gemm<<<dim3(512 * 12), dim3(256), 0, stream>>>(xb, wqkvT, qkv_b, qkvb);
    attn_kernel<<<dim3(4096), dim3(256), 0, stream>>>(qkvb, rpb, aoutb);
    proj_gemm<<<dim3(512 * 4), dim3(256), 0, stream>>>(aoutb, wprojT, proj_b, out);
}